// Round 1
// baseline (421.587 us; speedup 1.0000x reference)
//
#include <hip/hip_runtime.h>
#include <math.h>

// ---------------- CSR build ----------------

__global__ void k_count(const int* __restrict__ dst, int* __restrict__ cnt, int E) {
    int e = blockIdx.x * 256 + threadIdx.x;
    if (e < E) atomicAdd(&cnt[dst[e]], 1);
}

__global__ void k_dinv(const int* __restrict__ cnt, float* __restrict__ dinv, int N) {
    int i = blockIdx.x * 256 + threadIdx.x;
    if (i < N) dinv[i] = rsqrtf((float)(cnt[i] + 1));   // +1 = self loop; deg>0 always
}

__global__ void k_scan1(const int* __restrict__ cnt, int* __restrict__ offs,
                        int* __restrict__ bsum, int N) {
    __shared__ int sm[256];
    int t = threadIdx.x, i = blockIdx.x * 256 + t;
    int v = (i < N) ? cnt[i] : 0;
    sm[t] = v;
    __syncthreads();
    for (int off = 1; off < 256; off <<= 1) {
        int x = (t >= off) ? sm[t - off] : 0;
        __syncthreads();
        sm[t] += x;
        __syncthreads();
    }
    if (i < N) offs[i] = sm[t] - v;          // exclusive within block
    if (t == 255) bsum[blockIdx.x] = sm[255];
}

__global__ void k_scan2(const int* __restrict__ bsum, int* __restrict__ boff, int nb) {
    __shared__ int sm[256];
    int t = threadIdx.x;
    int v = (t < nb) ? bsum[t] : 0;
    sm[t] = v;
    __syncthreads();
    for (int off = 1; off < 256; off <<= 1) {
        int x = (t >= off) ? sm[t - off] : 0;
        __syncthreads();
        sm[t] += x;
        __syncthreads();
    }
    if (t < nb) boff[t] = sm[t] - v;
}

__global__ void k_scan3(int* __restrict__ offs, const int* __restrict__ boff, int N, int E) {
    int t = threadIdx.x, i = blockIdx.x * 256 + t;
    if (i < N) offs[i] += boff[blockIdx.x];
    if (blockIdx.x == 0 && t == 0) offs[N] = E;
}

__global__ void k_fill(const int* __restrict__ src, const int* __restrict__ dst,
                       const int* __restrict__ offs, int* __restrict__ cur,
                       const float* __restrict__ dinv, int2* __restrict__ csr, int E) {
    int e = blockIdx.x * 256 + threadIdx.x;
    if (e < E) {
        int s = src[e], d = dst[e];
        int p = offs[d] + atomicAdd(&cur[d], 1);
        csr[p] = make_int2(s, __float_as_int(dinv[s]));   // fold dinv[src] into entry
    }
}

// ---------------- GEMM: [n x 128] @ [128 x 128] (no bias/relu) ----------------
// block 256 threads, tile 64 rows x 128 cols, micro 4 rows x (4+4) cols.
__global__ __launch_bounds__(256) void k_gemm128(const float* __restrict__ A,
                                                 const float* __restrict__ W,
                                                 float* __restrict__ out, int nrows) {
    __shared__ float xs[16 * 64];    // [kk][row] transposed
    __shared__ float ws[16 * 128];   // [kk][c]
    int t = threadIdx.x;
    int tx = t & 15, ty = t >> 4;
    int r0 = blockIdx.x * 64;
    float acc[4][8] = {};
    for (int k0 = 0; k0 < 128; k0 += 16) {
        {   // stage A tile (transposed): thread -> row=t/4, kk0=(t%4)*4
            int row = t >> 2, kk0 = (t & 3) << 2;
            int gr = r0 + row;
            float4 v = make_float4(0.f, 0.f, 0.f, 0.f);
            if (gr < nrows) v = *(const float4*)&A[(size_t)gr * 128 + k0 + kk0];
            xs[(kk0 + 0) * 64 + row] = v.x;
            xs[(kk0 + 1) * 64 + row] = v.y;
            xs[(kk0 + 2) * 64 + row] = v.z;
            xs[(kk0 + 3) * 64 + row] = v.w;
        }
        {   // stage W chunk: 2048 floats, 2x float4 per thread
            int idx = t * 8;
            int kk = idx >> 7, c = idx & 127;
            *(float4*)&ws[kk * 128 + c]     = *(const float4*)&W[(k0 + kk) * 128 + c];
            *(float4*)&ws[kk * 128 + c + 4] = *(const float4*)&W[(k0 + kk) * 128 + c + 4];
        }
        __syncthreads();
#pragma unroll
        for (int kk = 0; kk < 16; ++kk) {
            float4 a  = *(const float4*)&xs[kk * 64 + ty * 4];
            float4 b0 = *(const float4*)&ws[kk * 128 + tx * 4];        // 2-way aliased: free
            float4 b1 = *(const float4*)&ws[kk * 128 + 64 + tx * 4];
            float av[4] = {a.x, a.y, a.z, a.w};
            float bv[8] = {b0.x, b0.y, b0.z, b0.w, b1.x, b1.y, b1.z, b1.w};
#pragma unroll
            for (int i = 0; i < 4; ++i)
#pragma unroll
                for (int j = 0; j < 8; ++j) acc[i][j] += av[i] * bv[j];
        }
        __syncthreads();
    }
    int r = r0 + ty * 4;
#pragma unroll
    for (int i = 0; i < 4; ++i) {
        if (r + i < nrows) {
            float4 v0 = make_float4(acc[i][0], acc[i][1], acc[i][2], acc[i][3]);
            float4 v1 = make_float4(acc[i][4], acc[i][5], acc[i][6], acc[i][7]);
            *(float4*)&out[(size_t)(r + i) * 128 + tx * 4]      = v0;
            *(float4*)&out[(size_t)(r + i) * 128 + 64 + tx * 4] = v1;
        }
    }
}

// ---------------- aggregation: out[n] = relu(dinv[n]*(sum_e h[src]*dinv[src] + h[n]*dinv[n]) + b)
__global__ __launch_bounds__(128) void k_agg(const float* __restrict__ hx,
                                             const int2* __restrict__ csr,
                                             const int* __restrict__ offs,
                                             const float* __restrict__ dinv,
                                             const float* __restrict__ bias,
                                             float* __restrict__ out) {
    int n = blockIdx.x, t = threadIdx.x;
    __shared__ int2 se[128];
    int s0 = offs[n], s1 = offs[n + 1];
    float di = dinv[n];
    float acc = hx[(size_t)n * 128 + t] * di;            // self-loop term (x di again below)
    for (int base = s0; base < s1; base += 128) {
        int idx = base + t;
        if (idx < s1) se[t] = csr[idx];
        __syncthreads();
        int lim = min(128, s1 - base);
        for (int j = 0; j < lim; ++j) {
            int2 en = se[j];
            acc += hx[(size_t)en.x * 128 + t] * __int_as_float(en.y);
        }
        __syncthreads();
    }
    float v = acc * di + bias[t];
    out[(size_t)n * 128 + t] = fmaxf(v, 0.f);
}

// ---------------- entity mean pool ----------------
__global__ __launch_bounds__(128) void k_pool(const float* __restrict__ h,
                                              const int* __restrict__ ent,
                                              float* __restrict__ out) {
    int r = blockIdx.x, t = threadIdx.x;
    float acc = 0.f;
    int cnt = 0;
#pragma unroll
    for (int m = 0; m < 20; ++m) {
        int id = ent[r * 20 + m];
        if (id >= 0) { acc += h[(size_t)id * 128 + t]; cnt++; }
    }
    out[(size_t)r * 128 + t] = acc / (float)max(cnt, 1);
}

// ---------------- MLP fc1: z = relu([bert|gnn] @ fc1_w + fc1_b) ----------------
// M=4096 (grid.x=64), N=448 (grid.y=7), K=896, KC=32, tile 64x64, micro 4x4.
__global__ __launch_bounds__(256) void k_mlp1(const float* __restrict__ bert,
                                              const float* __restrict__ gnn,
                                              const float* __restrict__ Wf,
                                              const float* __restrict__ bf,
                                              float* __restrict__ z) {
    __shared__ float as[32 * 64];   // [kk][row]
    __shared__ float bs[32 * 64];   // [kk][c]
    int t = threadIdx.x, tx = t & 15, ty = t >> 4;
    int r0 = blockIdx.x * 64;
    int c0 = blockIdx.y * 64;
    float acc[4][4] = {};
    for (int k0 = 0; k0 < 896; k0 += 32) {
        {   // stage A (virtual concat), transposed: row=t/4, kk0=(t%4)*8
            int row = t >> 2, kk0 = (t & 3) << 3;
            int gr = r0 + row;
            float4 v0, v1;
            if (k0 < 768) {   // chunks never straddle 768 (k0 multiple of 32)
                v0 = *(const float4*)&bert[(size_t)gr * 768 + k0 + kk0];
                v1 = *(const float4*)&bert[(size_t)gr * 768 + k0 + kk0 + 4];
            } else {
                v0 = *(const float4*)&gnn[(size_t)gr * 128 + (k0 - 768) + kk0];
                v1 = *(const float4*)&gnn[(size_t)gr * 128 + (k0 - 768) + kk0 + 4];
            }
            as[(kk0 + 0) * 64 + row] = v0.x;
            as[(kk0 + 1) * 64 + row] = v0.y;
            as[(kk0 + 2) * 64 + row] = v0.z;
            as[(kk0 + 3) * 64 + row] = v0.w;
            as[(kk0 + 4) * 64 + row] = v1.x;
            as[(kk0 + 5) * 64 + row] = v1.y;
            as[(kk0 + 6) * 64 + row] = v1.z;
            as[(kk0 + 7) * 64 + row] = v1.w;
        }
        {   // stage B: kk=t/8, c=(t%8)*8
            int kk = t >> 3, cc = (t & 7) << 3;
            *(float4*)&bs[kk * 64 + cc]     = *(const float4*)&Wf[(size_t)(k0 + kk) * 448 + c0 + cc];
            *(float4*)&bs[kk * 64 + cc + 4] = *(const float4*)&Wf[(size_t)(k0 + kk) * 448 + c0 + cc + 4];
        }
        __syncthreads();
#pragma unroll
        for (int kk = 0; kk < 32; ++kk) {
            float4 a = *(const float4*)&as[kk * 64 + ty * 4];
            float4 b = *(const float4*)&bs[kk * 64 + tx * 4];
            float av[4] = {a.x, a.y, a.z, a.w};
            float bv[4] = {b.x, b.y, b.z, b.w};
#pragma unroll
            for (int i = 0; i < 4; ++i)
#pragma unroll
                for (int j = 0; j < 4; ++j) acc[i][j] += av[i] * bv[j];
        }
        __syncthreads();
    }
    int r = r0 + ty * 4, c = c0 + tx * 4;
    float4 bb = *(const float4*)&bf[c];
#pragma unroll
    for (int i = 0; i < 4; ++i) {
        float4 v;
        v.x = fmaxf(acc[i][0] + bb.x, 0.f);
        v.y = fmaxf(acc[i][1] + bb.y, 0.f);
        v.z = fmaxf(acc[i][2] + bb.z, 0.f);
        v.w = fmaxf(acc[i][3] + bb.w, 0.f);
        *(float4*)&z[(size_t)(r + i) * 448 + c] = v;
    }
}

// ---------------- MLP fc2 + sigmoid: one wave per row ----------------
__global__ __launch_bounds__(64) void k_mlp2(const float* __restrict__ z,
                                             const float* __restrict__ w,
                                             const float* __restrict__ b,
                                             float* __restrict__ out) {
    int r = blockIdx.x, t = threadIdx.x;
    float acc = 0.f;
#pragma unroll
    for (int i = 0; i < 7; ++i) {
        int c = t + i * 64;
        acc += z[(size_t)r * 448 + c] * w[c];
    }
#pragma unroll
    for (int off = 32; off > 0; off >>= 1) acc += __shfl_down(acc, off, 64);
    if (t == 0) {
        float lg = acc + b[0];
        out[r] = 1.f / (1.f + expf(-lg));
    }
}

extern "C" void kernel_launch(void* const* d_in, const int* in_sizes, int n_in,
                              void* d_out, int out_size, void* d_ws, size_t ws_size,
                              hipStream_t stream) {
    const float* bert = (const float*)d_in[0];
    const float* x    = (const float*)d_in[1];
    const int*   ei   = (const int*)d_in[2];
    const int*   ent  = (const int*)d_in[3];
    const float* W1   = (const float*)d_in[4];
    const float* b1   = (const float*)d_in[5];
    const float* W2   = (const float*)d_in[6];
    const float* b2   = (const float*)d_in[7];
    const float* fc1w = (const float*)d_in[8];
    const float* fc1b = (const float*)d_in[9];
    const float* fc2w = (const float*)d_in[10];
    const float* fc2b = (const float*)d_in[11];
    float* out = (float*)d_out;

    const int N = in_sizes[1] / 128;   // 50000 nodes
    const int E = in_sizes[2] / 2;     // 800000 edges
    const int B = in_sizes[0] / 768;   // 4096 batch

    const int* srcv = ei;
    const int* dstv = ei + E;

    char* wsp = (char*)d_ws;
    size_t off = 0;
    auto alloc = [&](size_t bytes) -> void* {
        void* p = wsp + off;
        off += (bytes + 255) & ~(size_t)255;
        return p;
    };
    float* dinv  = (float*)alloc((size_t)N * 4);
    int*   incnt = (int*)alloc((size_t)N * 4);
    int*   cur   = (int*)alloc((size_t)N * 4);
    int*   offs  = (int*)alloc((size_t)(N + 1) * 4);
    int*   bsum  = (int*)alloc(256 * 4);
    int*   boff  = (int*)alloc(256 * 4);
    int2*  csr   = (int2*)alloc((size_t)E * 8);
    float* hA    = (float*)alloc((size_t)N * 128 * 4);
    float* hB    = (float*)alloc((size_t)N * 128 * 4);
    float* gnn   = (float*)alloc((size_t)B * 128 * 4);
    float* zbuf  = (float*)alloc((size_t)B * 448 * 4);
    (void)ws_size; (void)n_in; (void)out_size;

    hipMemsetAsync(incnt, 0, (size_t)N * 4, stream);
    hipMemsetAsync(cur, 0, (size_t)N * 4, stream);

    int nb = (N + 255) / 256;
    k_count<<<(E + 255) / 256, 256, 0, stream>>>(dstv, incnt, E);
    k_dinv <<<nb, 256, 0, stream>>>(incnt, dinv, N);
    k_scan1<<<nb, 256, 0, stream>>>(incnt, offs, bsum, N);
    k_scan2<<<1, 256, 0, stream>>>(bsum, boff, nb);
    k_scan3<<<nb, 256, 0, stream>>>(offs, boff, N, E);
    k_fill <<<(E + 255) / 256, 256, 0, stream>>>(srcv, dstv, offs, cur, dinv, csr, E);

    int gb = (N + 63) / 64;
    k_gemm128<<<gb, 256, 0, stream>>>(x, W1, hA, N);
    k_agg<<<N, 128, 0, stream>>>(hA, csr, offs, dinv, b1, hB);
    k_gemm128<<<gb, 256, 0, stream>>>(hB, W2, hA, N);
    k_agg<<<N, 128, 0, stream>>>(hA, csr, offs, dinv, b2, hB);
    k_pool<<<B, 128, 0, stream>>>(hB, ent, gnn);
    k_mlp1<<<dim3(B / 64, 7), 256, 0, stream>>>(bert, gnn, fc1w, fc1b, zbuf);
    k_mlp2<<<B, 64, 0, stream>>>(zbuf, fc2w, fc2b, out);
}

// Round 2
// 355.078 us; speedup vs baseline: 1.1873x; 1.1873x over previous
//
#include <hip/hip_runtime.h>
#include <math.h>

typedef __bf16 bf16_t;
typedef __bf16 bfrag8 __attribute__((ext_vector_type(8)));
typedef float  facc4  __attribute__((ext_vector_type(4)));

__device__ inline unsigned short f2b(float x) {          // RNE float->bf16 bits
    unsigned int u = __float_as_uint(x);
    unsigned int r = (u + 0x7fffu + ((u >> 16) & 1u)) >> 16;
    return (unsigned short)r;
}
__device__ inline unsigned int pack2(float lo, float hi) {
    return (unsigned int)f2b(lo) | ((unsigned int)f2b(hi) << 16);
}
__device__ inline float blo(unsigned int q) { return __uint_as_float(q << 16); }
__device__ inline float bhi(unsigned int q) { return __uint_as_float(q & 0xffff0000u); }

// ---------------- CSR build ----------------

__global__ void k_count(const int* __restrict__ dst, int* __restrict__ cnt, int E) {
    int e = blockIdx.x * 256 + threadIdx.x;
    if (e < E) atomicAdd(&cnt[dst[e]], 1);
}

__global__ void k_dinv(const int* __restrict__ cnt, float* __restrict__ dinv, int N) {
    int i = blockIdx.x * 256 + threadIdx.x;
    if (i < N) dinv[i] = rsqrtf((float)(cnt[i] + 1));   // +1 = self loop
}

__global__ void k_scan1(const int* __restrict__ cnt, int* __restrict__ offs,
                        int* __restrict__ bsum, int N) {
    __shared__ int sm[256];
    int t = threadIdx.x, i = blockIdx.x * 256 + t;
    int v = (i < N) ? cnt[i] : 0;
    sm[t] = v;
    __syncthreads();
    for (int off = 1; off < 256; off <<= 1) {
        int x = (t >= off) ? sm[t - off] : 0;
        __syncthreads();
        sm[t] += x;
        __syncthreads();
    }
    if (i < N) offs[i] = sm[t] - v;
    if (t == 255) bsum[blockIdx.x] = sm[255];
}

__global__ void k_scan2(const int* __restrict__ bsum, int* __restrict__ boff, int nb) {
    __shared__ int sm[256];
    int t = threadIdx.x;
    int v = (t < nb) ? bsum[t] : 0;
    sm[t] = v;
    __syncthreads();
    for (int off = 1; off < 256; off <<= 1) {
        int x = (t >= off) ? sm[t - off] : 0;
        __syncthreads();
        sm[t] += x;
        __syncthreads();
    }
    if (t < nb) boff[t] = sm[t] - v;
}

__global__ void k_scan3(int* __restrict__ offs, const int* __restrict__ boff, int N, int E) {
    int t = threadIdx.x, i = blockIdx.x * 256 + t;
    if (i < N) offs[i] += boff[blockIdx.x];
    if (blockIdx.x == 0 && t == 0) offs[N] = E;
}

__global__ void k_fill(const int* __restrict__ src, const int* __restrict__ dst,
                       const int* __restrict__ offs, int* __restrict__ cur,
                       const float* __restrict__ dinv, int2* __restrict__ csr, int E) {
    int e = blockIdx.x * 256 + threadIdx.x;
    if (e < E) {
        int s = src[e], d = dst[e];
        int p = offs[d] + atomicAdd(&cur[d], 1);
        csr[p] = make_int2(s, __float_as_int(dinv[s]));
    }
}

// ---------------- fp32 -> bf16 conversion (8 elems/thread) ----------------
__global__ void k_cvt(const float* __restrict__ in, unsigned int* __restrict__ outb, int n8) {
    int i = blockIdx.x * 256 + threadIdx.x;
    if (i >= n8) return;
    const float4* p = (const float4*)in + (size_t)i * 2;
    float4 a = p[0], b = p[1];
    uint4 o;
    o.x = pack2(a.x, a.y);
    o.y = pack2(a.z, a.w);
    o.z = pack2(b.x, b.y);
    o.w = pack2(b.z, b.w);
    ((uint4*)outb)[i] = o;
}

// ---------------- weight transpose + cvt: Wt[n][k] = (bf16)W[k][n] ----------------
__global__ void k_prep_wt(const float* __restrict__ W, unsigned short* __restrict__ Wt,
                          int K, int N) {
    int idx = blockIdx.x * 256 + threadIdx.x;
    if (idx >= K * N) return;
    int n = idx / K, k = idx - n * K;
    Wt[idx] = f2b(W[(size_t)k * N + n]);
}

// ---------------- MFMA GEMM: [M x 128](bf16) @ Bt[128][128](bf16) -> [M x 128](bf16)
// block 256 = 4 waves; tile 64 rows x 128 cols; wave w: rows 16w..16w+15, all 128 cols.
__global__ __launch_bounds__(256) void k_gemm_nn128(const bf16_t* __restrict__ A,
                                                    const bf16_t* __restrict__ Bt,
                                                    bf16_t* __restrict__ out, int M) {
    __shared__ bf16_t As[64 * 136];    // +8 bf16 pad: row stride 272B (16B-aligned, 2-way banks)
    __shared__ bf16_t Bs[128 * 136];
    int t = threadIdx.x;
    int wave = t >> 6, lane = t & 63, quad = lane >> 4, l16 = lane & 15;
    int r0 = blockIdx.x * 64;
    // stage A: 1024 chunks of 16B, 4/thread
#pragma unroll
    for (int i = 0; i < 4; ++i) {
        int chunk = t + i * 256;
        int row = chunk >> 4, c8 = (chunk & 15) << 3;
        int gr = r0 + row;
        uint4 v = make_uint4(0u, 0u, 0u, 0u);
        if (gr < M) v = *(const uint4*)&A[(size_t)gr * 128 + c8];
        *(uint4*)&As[row * 136 + c8] = v;
    }
    // stage B: 2048 chunks, 8/thread
#pragma unroll
    for (int i = 0; i < 8; ++i) {
        int chunk = t + i * 256;
        int row = chunk >> 4, c8 = (chunk & 15) << 3;
        *(uint4*)&Bs[row * 136 + c8] = *(const uint4*)&Bt[row * 128 + c8];
    }
    __syncthreads();

    facc4 acc[8];
#pragma unroll
    for (int nt = 0; nt < 8; ++nt) acc[nt] = (facc4){0.f, 0.f, 0.f, 0.f};
    int arow = (wave << 4) + l16;
#pragma unroll
    for (int ks = 0; ks < 4; ++ks) {
        int kk = ks * 32 + quad * 8;
        bfrag8 af = *(const bfrag8*)&As[arow * 136 + kk];
#pragma unroll
        for (int nt = 0; nt < 8; ++nt) {
            bfrag8 bf = *(const bfrag8*)&Bs[(nt * 16 + l16) * 136 + kk];
            acc[nt] = __builtin_amdgcn_mfma_f32_16x16x32_bf16(af, bf, acc[nt], 0, 0, 0);
        }
    }
    int rbase = r0 + (wave << 4) + quad * 4;
#pragma unroll
    for (int nt = 0; nt < 8; ++nt) {
        int col = nt * 16 + l16;
#pragma unroll
        for (int r = 0; r < 4; ++r) {
            int row = rbase + r;
            if (row < M) {
                unsigned short b = f2b(acc[nt][r]);
                ((unsigned short*)out)[(size_t)row * 128 + col] = b;
            }
        }
    }
}

// ---------------- aggregation (bf16 h): wave per node ----------------
// out[n][:] = relu(dinv[n]*(sum_e h[src]*dinv[src] + h[n]*dinv[n]) + bias)
__global__ __launch_bounds__(256) void k_agg_b(const unsigned int* __restrict__ hx,  // [N][64] uints
                                               const int2* __restrict__ csr,
                                               const int* __restrict__ offs,
                                               const float* __restrict__ dinv,
                                               const float* __restrict__ bias,
                                               unsigned int* __restrict__ out, int N) {
    int node = blockIdx.x * 4 + (threadIdx.x >> 6);
    int lane = threadIdx.x & 63;
    if (node >= N) return;
    float di = dinv[node];
    unsigned int q = hx[(size_t)node * 64 + lane];
    float acc0 = blo(q) * di, acc1 = bhi(q) * di;     // self-loop (x di again at end)
    int s0 = offs[node], s1 = offs[node + 1];
    for (int base = s0; base < s1; base += 64) {
        int nloc = min(64, s1 - base);
        int2 en = make_int2(0, 0);
        if (lane < nloc) en = csr[base + lane];
        for (int j = 0; j < nloc; ++j) {
            int srcn = __shfl(en.x, j, 64);
            float w  = __int_as_float(__shfl(en.y, j, 64));
            unsigned int g = hx[(size_t)srcn * 64 + lane];
            acc0 += blo(g) * w;
            acc1 += bhi(g) * w;
        }
    }
    float2 bb = *(const float2*)&bias[lane * 2];
    float v0 = fmaxf(acc0 * di + bb.x, 0.f);
    float v1 = fmaxf(acc1 * di + bb.y, 0.f);
    out[(size_t)node * 64 + lane] = pack2(v0, v1);
}

// ---------------- entity mean pool (bf16 in/out): wave per row ----------------
__global__ __launch_bounds__(256) void k_pool_b(const unsigned int* __restrict__ h,
                                                const int* __restrict__ ent,
                                                unsigned int* __restrict__ out) {
    int r = blockIdx.x * 4 + (threadIdx.x >> 6);
    int lane = threadIdx.x & 63;
    float a0 = 0.f, a1 = 0.f;
    int cnt = 0;
#pragma unroll
    for (int m = 0; m < 20; ++m) {
        int id = ent[r * 20 + m];
        if (id >= 0) {
            unsigned int q = h[(size_t)id * 64 + lane];
            a0 += blo(q); a1 += bhi(q); cnt++;
        }
    }
    float inv = 1.f / (float)max(cnt, 1);
    out[(size_t)r * 64 + lane] = pack2(a0 * inv, a1 * inv);
}

// ---------------- MLP fc1 (MFMA): z = relu([bertb|gnnb] @ fc1wt + fc1_b), z fp32
// grid (4096/64, 448/64=7); BK=128, 7 k-steps (6 bert + 1 gnn).
__global__ __launch_bounds__(256) void k_mlp1_mfma(const bf16_t* __restrict__ bertb,
                                                   const bf16_t* __restrict__ gnnb,
                                                   const bf16_t* __restrict__ fwt,  // [448][896]
                                                   const float* __restrict__ fb,
                                                   float* __restrict__ z) {
    __shared__ bf16_t As[64 * 136];
    __shared__ bf16_t Bs[64 * 136];
    int t = threadIdx.x;
    int wave = t >> 6, lane = t & 63, quad = lane >> 4, l16 = lane & 15;
    int r0 = blockIdx.x * 64, c0 = blockIdx.y * 64;
    facc4 acc[4];
#pragma unroll
    for (int nt = 0; nt < 4; ++nt) acc[nt] = (facc4){0.f, 0.f, 0.f, 0.f};

    for (int ks = 0; ks < 7; ++ks) {
#pragma unroll
        for (int i = 0; i < 4; ++i) {           // stage A tile 64x128
            int chunk = t + i * 256;
            int row = chunk >> 4, c8 = (chunk & 15) << 3;
            int gr = r0 + row;
            const bf16_t* srcp = (ks < 6) ? &bertb[(size_t)gr * 768 + ks * 128 + c8]
                                          : &gnnb[(size_t)gr * 128 + c8];
            *(uint4*)&As[row * 136 + c8] = *(const uint4*)srcp;
        }
#pragma unroll
        for (int i = 0; i < 4; ++i) {           // stage B tile 64x128
            int chunk = t + i * 256;
            int row = chunk >> 4, c8 = (chunk & 15) << 3;
            *(uint4*)&Bs[row * 136 + c8] =
                *(const uint4*)&fwt[(size_t)(c0 + row) * 896 + ks * 128 + c8];
        }
        __syncthreads();
        int arow = (wave << 4) + l16;
#pragma unroll
        for (int sub = 0; sub < 4; ++sub) {
            int kk = sub * 32 + quad * 8;
            bfrag8 af = *(const bfrag8*)&As[arow * 136 + kk];
#pragma unroll
            for (int nt = 0; nt < 4; ++nt) {
                bfrag8 bf = *(const bfrag8*)&Bs[(nt * 16 + l16) * 136 + kk];
                acc[nt] = __builtin_amdgcn_mfma_f32_16x16x32_bf16(af, bf, acc[nt], 0, 0, 0);
            }
        }
        __syncthreads();
    }
    int rbase = r0 + (wave << 4) + quad * 4;
#pragma unroll
    for (int nt = 0; nt < 4; ++nt) {
        int col = c0 + nt * 16 + l16;
        float bb = fb[col];
#pragma unroll
        for (int r = 0; r < 4; ++r)
            z[(size_t)(rbase + r) * 448 + col] = fmaxf(acc[nt][r] + bb, 0.f);
    }
}

// ---------------- MLP fc2 + sigmoid: wave per row, 4 rows/block ----------------
__global__ __launch_bounds__(256) void k_mlp2(const float* __restrict__ z,
                                              const float* __restrict__ w,
                                              const float* __restrict__ b,
                                              float* __restrict__ out) {
    int r = blockIdx.x * 4 + (threadIdx.x >> 6);
    int lane = threadIdx.x & 63;
    float acc = 0.f;
#pragma unroll
    for (int i = 0; i < 7; ++i) {
        int c = lane + i * 64;
        acc += z[(size_t)r * 448 + c] * w[c];
    }
#pragma unroll
    for (int off = 32; off > 0; off >>= 1) acc += __shfl_down(acc, off, 64);
    if (lane == 0) {
        float lg = acc + b[0];
        out[r] = 1.f / (1.f + expf(-lg));
    }
}

extern "C" void kernel_launch(void* const* d_in, const int* in_sizes, int n_in,
                              void* d_out, int out_size, void* d_ws, size_t ws_size,
                              hipStream_t stream) {
    const float* bert = (const float*)d_in[0];
    const float* x    = (const float*)d_in[1];
    const int*   ei   = (const int*)d_in[2];
    const int*   ent  = (const int*)d_in[3];
    const float* W1   = (const float*)d_in[4];
    const float* b1   = (const float*)d_in[5];
    const float* W2   = (const float*)d_in[6];
    const float* b2   = (const float*)d_in[7];
    const float* fc1w = (const float*)d_in[8];
    const float* fc1b = (const float*)d_in[9];
    const float* fc2w = (const float*)d_in[10];
    const float* fc2b = (const float*)d_in[11];
    float* out = (float*)d_out;

    const int N = in_sizes[1] / 128;   // 50000
    const int E = in_sizes[2] / 2;     // 800000
    const int B = in_sizes[0] / 768;   // 4096

    const int* srcv = ei;
    const int* dstv = ei + E;

    char* wsp = (char*)d_ws;
    size_t off = 0;
    auto alloc = [&](size_t bytes) -> void* {
        void* p = wsp + off;
        off += (bytes + 255) & ~(size_t)255;
        return p;
    };
    float* dinv   = (float*)alloc((size_t)N * 4);
    int*   incnt  = (int*)alloc((size_t)N * 4);
    int*   cur    = (int*)alloc((size_t)N * 4);
    int*   offs   = (int*)alloc((size_t)(N + 1) * 4);
    int*   bsum   = (int*)alloc(256 * 4);
    int*   boff   = (int*)alloc(256 * 4);
    int2*  csr    = (int2*)alloc((size_t)E * 8);
    bf16_t* xb    = (bf16_t*)alloc((size_t)N * 128 * 2);
    bf16_t* bertb = (bf16_t*)alloc((size_t)B * 768 * 2);
    bf16_t* w1t   = (bf16_t*)alloc(128 * 128 * 2);
    bf16_t* w2t   = (bf16_t*)alloc(128 * 128 * 2);
    bf16_t* fwt   = (bf16_t*)alloc((size_t)896 * 448 * 2);
    bf16_t* gbuf  = (bf16_t*)alloc((size_t)N * 128 * 2);   // gemm out (pre-bias)
    bf16_t* hbuf  = (bf16_t*)alloc((size_t)N * 128 * 2);   // agg out (post-relu)
    bf16_t* gnnb  = (bf16_t*)alloc((size_t)B * 128 * 2);
    float* zbuf   = (float*)alloc((size_t)B * 448 * 4);
    (void)ws_size; (void)n_in; (void)out_size;

    hipMemsetAsync(incnt, 0, (size_t)N * 4, stream);
    hipMemsetAsync(cur, 0, (size_t)N * 4, stream);

    int nb = (N + 255) / 256;
    k_count<<<(E + 255) / 256, 256, 0, stream>>>(dstv, incnt, E);
    k_dinv <<<nb, 256, 0, stream>>>(incnt, dinv, N);
    k_scan1<<<nb, 256, 0, stream>>>(incnt, offs, bsum, N);
    k_scan2<<<1, 256, 0, stream>>>(bsum, boff, nb);
    k_scan3<<<nb, 256, 0, stream>>>(offs, boff, N, E);
    k_fill <<<(E + 255) / 256, 256, 0, stream>>>(srcv, dstv, offs, cur, dinv, csr, E);

    // dtype prep
    int nx8 = N * 128 / 8, nb8 = B * 768 / 8;
    k_cvt<<<(nx8 + 255) / 256, 256, 0, stream>>>(x, (unsigned int*)xb, nx8);
    k_cvt<<<(nb8 + 255) / 256, 256, 0, stream>>>(bert, (unsigned int*)bertb, nb8);
    k_prep_wt<<<(128 * 128 + 255) / 256, 256, 0, stream>>>(W1, (unsigned short*)w1t, 128, 128);
    k_prep_wt<<<(128 * 128 + 255) / 256, 256, 0, stream>>>(W2, (unsigned short*)w2t, 128, 128);
    k_prep_wt<<<(896 * 448 + 255) / 256, 256, 0, stream>>>(fc1w, (unsigned short*)fwt, 896, 448);

    int gb = (N + 63) / 64;
    k_gemm_nn128<<<gb, 256, 0, stream>>>(xb, w1t, gbuf, N);
    k_agg_b<<<(N + 3) / 4, 256, 0, stream>>>((const unsigned int*)gbuf, csr, offs, dinv, b1,
                                             (unsigned int*)hbuf, N);
    k_gemm_nn128<<<gb, 256, 0, stream>>>(hbuf, w2t, gbuf, N);
    k_agg_b<<<(N + 3) / 4, 256, 0, stream>>>((const unsigned int*)gbuf, csr, offs, dinv, b2,
                                             (unsigned int*)hbuf, N);
    k_pool_b<<<B / 4, 256, 0, stream>>>((const unsigned int*)hbuf, ent, (unsigned int*)gnnb);
    k_mlp1_mfma<<<dim3(B / 64, 7), 256, 0, stream>>>(bertb, gnnb, fwt, fc1b, zbuf);
    k_mlp2<<<B / 4, 256, 0, stream>>>(zbuf, fc2w, fc2b, out);
}

// Round 3
// 310.292 us; speedup vs baseline: 1.3587x; 1.1443x over previous
//
#include <hip/hip_runtime.h>
#include <math.h>

typedef __bf16 bf16_t;
typedef __bf16 bfrag8 __attribute__((ext_vector_type(8)));
typedef float  facc4  __attribute__((ext_vector_type(4)));

__device__ inline unsigned short f2b(float x) {          // RNE float->bf16 bits
    unsigned int u = __float_as_uint(x);
    unsigned int r = (u + 0x7fffu + ((u >> 16) & 1u)) >> 16;
    return (unsigned short)r;
}
__device__ inline unsigned int pack2(float lo, float hi) {
    return (unsigned int)f2b(lo) | ((unsigned int)f2b(hi) << 16);
}
__device__ inline float blo(unsigned int q) { return __uint_as_float(q << 16); }
__device__ inline float bhi(unsigned int q) { return __uint_as_float(q & 0xffff0000u); }

// ---------------- CSR build ----------------

__global__ void k_count(const int* __restrict__ dst, int* __restrict__ cnt, int E) {
    int e = blockIdx.x * 256 + threadIdx.x;
    if (e < E) atomicAdd(&cnt[dst[e]], 1);
}

__global__ void k_dinv(const int* __restrict__ cnt, float* __restrict__ dinv, int N) {
    int i = blockIdx.x * 256 + threadIdx.x;
    if (i < N) dinv[i] = rsqrtf((float)(cnt[i] + 1));   // +1 = self loop
}

__global__ void k_scan1(const int* __restrict__ cnt, int* __restrict__ offs,
                        int* __restrict__ bsum, int N) {
    __shared__ int sm[256];
    int t = threadIdx.x, i = blockIdx.x * 256 + t;
    int v = (i < N) ? cnt[i] : 0;
    sm[t] = v;
    __syncthreads();
    for (int off = 1; off < 256; off <<= 1) {
        int x = (t >= off) ? sm[t - off] : 0;
        __syncthreads();
        sm[t] += x;
        __syncthreads();
    }
    if (i < N) offs[i] = sm[t] - v;
    if (t == 255) bsum[blockIdx.x] = sm[255];
}

__global__ void k_scan2(const int* __restrict__ bsum, int* __restrict__ boff, int nb) {
    __shared__ int sm[256];
    int t = threadIdx.x;
    int v = (t < nb) ? bsum[t] : 0;
    sm[t] = v;
    __syncthreads();
    for (int off = 1; off < 256; off <<= 1) {
        int x = (t >= off) ? sm[t - off] : 0;
        __syncthreads();
        sm[t] += x;
        __syncthreads();
    }
    if (t < nb) boff[t] = sm[t] - v;
}

__global__ void k_scan3(int* __restrict__ offs, const int* __restrict__ boff, int N, int E) {
    int t = threadIdx.x, i = blockIdx.x * 256 + t;
    if (i < N) offs[i] += boff[blockIdx.x];
    if (blockIdx.x == 0 && t == 0) offs[N] = E;
}

__global__ void k_fill(const int* __restrict__ src, const int* __restrict__ dst,
                       const int* __restrict__ offs, int* __restrict__ cur,
                       const float* __restrict__ dinv, int2* __restrict__ csr, int E) {
    int e = blockIdx.x * 256 + threadIdx.x;
    if (e < E) {
        int s = src[e], d = dst[e];
        int p = offs[d] + atomicAdd(&cur[d], 1);
        csr[p] = make_int2(s, __float_as_int(dinv[s]));
    }
}

// ---------------- fp32 -> bf16 conversion (8 elems/thread) ----------------
__global__ void k_cvt(const float* __restrict__ in, unsigned int* __restrict__ outb, int n8) {
    int i = blockIdx.x * 256 + threadIdx.x;
    if (i >= n8) return;
    const float4* p = (const float4*)in + (size_t)i * 2;
    float4 a = p[0], b = p[1];
    uint4 o;
    o.x = pack2(a.x, a.y);
    o.y = pack2(a.z, a.w);
    o.z = pack2(b.x, b.y);
    o.w = pack2(b.z, b.w);
    ((uint4*)outb)[i] = o;
}

// ---------------- weight transpose + cvt: Wt[n][k] = (bf16)W[k][n] ----------------
__global__ void k_prep_wt(const float* __restrict__ W, unsigned short* __restrict__ Wt,
                          int K, int N) {
    int idx = blockIdx.x * 256 + threadIdx.x;
    if (idx >= K * N) return;
    int n = idx / K, k = idx - n * K;
    Wt[idx] = f2b(W[(size_t)k * N + n]);
}

// ---------------- MFMA GEMM: [M x 128](bf16) @ Bt[128][128](bf16) -> [M x 128](bf16)
__global__ __launch_bounds__(256) void k_gemm_nn128(const bf16_t* __restrict__ A,
                                                    const bf16_t* __restrict__ Bt,
                                                    bf16_t* __restrict__ out, int M) {
    __shared__ bf16_t As[64 * 136];
    __shared__ bf16_t Bs[128 * 136];
    int t = threadIdx.x;
    int wave = t >> 6, lane = t & 63, quad = lane >> 4, l16 = lane & 15;
    int r0 = blockIdx.x * 64;
#pragma unroll
    for (int i = 0; i < 4; ++i) {
        int chunk = t + i * 256;
        int row = chunk >> 4, c8 = (chunk & 15) << 3;
        int gr = r0 + row;
        uint4 v = make_uint4(0u, 0u, 0u, 0u);
        if (gr < M) v = *(const uint4*)&A[(size_t)gr * 128 + c8];
        *(uint4*)&As[row * 136 + c8] = v;
    }
#pragma unroll
    for (int i = 0; i < 8; ++i) {
        int chunk = t + i * 256;
        int row = chunk >> 4, c8 = (chunk & 15) << 3;
        *(uint4*)&Bs[row * 136 + c8] = *(const uint4*)&Bt[row * 128 + c8];
    }
    __syncthreads();

    facc4 acc[8];
#pragma unroll
    for (int nt = 0; nt < 8; ++nt) acc[nt] = (facc4){0.f, 0.f, 0.f, 0.f};
    int arow = (wave << 4) + l16;
#pragma unroll
    for (int ks = 0; ks < 4; ++ks) {
        int kk = ks * 32 + quad * 8;
        bfrag8 af = *(const bfrag8*)&As[arow * 136 + kk];
#pragma unroll
        for (int nt = 0; nt < 8; ++nt) {
            bfrag8 bf = *(const bfrag8*)&Bs[(nt * 16 + l16) * 136 + kk];
            acc[nt] = __builtin_amdgcn_mfma_f32_16x16x32_bf16(af, bf, acc[nt], 0, 0, 0);
        }
    }
    int rbase = r0 + (wave << 4) + quad * 4;
#pragma unroll
    for (int nt = 0; nt < 8; ++nt) {
        int col = nt * 16 + l16;
#pragma unroll
        for (int r = 0; r < 4; ++r) {
            int row = rbase + r;
            if (row < M) {
                unsigned short b = f2b(acc[nt][r]);
                ((unsigned short*)out)[(size_t)row * 128 + col] = b;
            }
        }
    }
}

// ---------------- aggregation (bf16 h): wave per node, 8-way MLP unroll ----------------
__global__ __launch_bounds__(256) void k_agg_b(const unsigned int* __restrict__ hx,  // [N][64]
                                               const int2* __restrict__ csr,
                                               const int* __restrict__ offs,
                                               const float* __restrict__ dinv,
                                               const float* __restrict__ bias,
                                               unsigned int* __restrict__ out, int N) {
    int node = blockIdx.x * 4 + (threadIdx.x >> 6);
    int lane = threadIdx.x & 63;
    if (node >= N) return;
    float di = dinv[node];
    unsigned int q = hx[(size_t)node * 64 + lane];
    float acc0 = blo(q) * di, acc1 = bhi(q) * di;     // self-loop (x di again at end)
    int s0 = offs[node], s1 = offs[node + 1];
    for (int base = s0; base < s1; base += 64) {
        int nloc = min(64, s1 - base);
        int2 en = make_int2(0, 0);
        if (lane < nloc) en = csr[base + lane];
        int j = 0;
        for (; j + 8 <= nloc; j += 8) {
            int sid[8]; float w[8]; unsigned int g[8];
#pragma unroll
            for (int u = 0; u < 8; ++u) {
                sid[u] = __shfl(en.x, j + u, 64);
                w[u]   = __int_as_float(__shfl(en.y, j + u, 64));
            }
#pragma unroll
            for (int u = 0; u < 8; ++u) g[u] = hx[(size_t)sid[u] * 64 + lane];  // 8 in flight
#pragma unroll
            for (int u = 0; u < 8; ++u) { acc0 += blo(g[u]) * w[u]; acc1 += bhi(g[u]) * w[u]; }
        }
        // tail: up to 7 edges, 4-then-1
        for (; j + 4 <= nloc; j += 4) {
            int sid[4]; float w[4]; unsigned int g[4];
#pragma unroll
            for (int u = 0; u < 4; ++u) {
                sid[u] = __shfl(en.x, j + u, 64);
                w[u]   = __int_as_float(__shfl(en.y, j + u, 64));
            }
#pragma unroll
            for (int u = 0; u < 4; ++u) g[u] = hx[(size_t)sid[u] * 64 + lane];
#pragma unroll
            for (int u = 0; u < 4; ++u) { acc0 += blo(g[u]) * w[u]; acc1 += bhi(g[u]) * w[u]; }
        }
        for (; j < nloc; ++j) {
            int srcn = __shfl(en.x, j, 64);
            float w  = __int_as_float(__shfl(en.y, j, 64));
            unsigned int g = hx[(size_t)srcn * 64 + lane];
            acc0 += blo(g) * w;
            acc1 += bhi(g) * w;
        }
    }
    float2 bb = *(const float2*)&bias[lane * 2];
    float v0 = fmaxf(acc0 * di + bb.x, 0.f);
    float v1 = fmaxf(acc1 * di + bb.y, 0.f);
    out[(size_t)node * 64 + lane] = pack2(v0, v1);
}

// ---------------- entity mean pool (bf16 in/out): wave per row ----------------
__global__ __launch_bounds__(256) void k_pool_b(const unsigned int* __restrict__ h,
                                                const int* __restrict__ ent,
                                                unsigned int* __restrict__ out) {
    int r = blockIdx.x * 4 + (threadIdx.x >> 6);
    int lane = threadIdx.x & 63;
    float a0 = 0.f, a1 = 0.f;
    int cnt = 0;
#pragma unroll
    for (int m = 0; m < 20; ++m) {
        int id = ent[r * 20 + m];
        if (id >= 0) {
            unsigned int q = h[(size_t)id * 64 + lane];
            a0 += blo(q); a1 += bhi(q); cnt++;
        }
    }
    float inv = 1.f / (float)max(cnt, 1);
    out[(size_t)r * 64 + lane] = pack2(a0 * inv, a1 * inv);
}

// ---------------- MLP fc1 (MFMA): z = relu([bertb|gnnb] @ fc1wt + fc1_b), z fp32
__global__ __launch_bounds__(256) void k_mlp1_mfma(const bf16_t* __restrict__ bertb,
                                                   const bf16_t* __restrict__ gnnb,
                                                   const bf16_t* __restrict__ fwt,  // [448][896]
                                                   const float* __restrict__ fb,
                                                   float* __restrict__ z) {
    __shared__ bf16_t As[64 * 136];
    __shared__ bf16_t Bs[64 * 136];
    int t = threadIdx.x;
    int wave = t >> 6, lane = t & 63, quad = lane >> 4, l16 = lane & 15;
    int r0 = blockIdx.x * 64, c0 = blockIdx.y * 64;
    facc4 acc[4];
#pragma unroll
    for (int nt = 0; nt < 4; ++nt) acc[nt] = (facc4){0.f, 0.f, 0.f, 0.f};

    for (int ks = 0; ks < 7; ++ks) {
#pragma unroll
        for (int i = 0; i < 4; ++i) {
            int chunk = t + i * 256;
            int row = chunk >> 4, c8 = (chunk & 15) << 3;
            int gr = r0 + row;
            const bf16_t* srcp = (ks < 6) ? &bertb[(size_t)gr * 768 + ks * 128 + c8]
                                          : &gnnb[(size_t)gr * 128 + c8];
            *(uint4*)&As[row * 136 + c8] = *(const uint4*)srcp;
        }
#pragma unroll
        for (int i = 0; i < 4; ++i) {
            int chunk = t + i * 256;
            int row = chunk >> 4, c8 = (chunk & 15) << 3;
            *(uint4*)&Bs[row * 136 + c8] =
                *(const uint4*)&fwt[(size_t)(c0 + row) * 896 + ks * 128 + c8];
        }
        __syncthreads();
        int arow = (wave << 4) + l16;
#pragma unroll
        for (int sub = 0; sub < 4; ++sub) {
            int kk = sub * 32 + quad * 8;
            bfrag8 af = *(const bfrag8*)&As[arow * 136 + kk];
#pragma unroll
            for (int nt = 0; nt < 4; ++nt) {
                bfrag8 bf = *(const bfrag8*)&Bs[(nt * 16 + l16) * 136 + kk];
                acc[nt] = __builtin_amdgcn_mfma_f32_16x16x32_bf16(af, bf, acc[nt], 0, 0, 0);
            }
        }
        __syncthreads();
    }
    int rbase = r0 + (wave << 4) + quad * 4;
#pragma unroll
    for (int nt = 0; nt < 4; ++nt) {
        int col = c0 + nt * 16 + l16;
        float bb = fb[col];
#pragma unroll
        for (int r = 0; r < 4; ++r)
            z[(size_t)(rbase + r) * 448 + col] = fmaxf(acc[nt][r] + bb, 0.f);
    }
}

// ---------------- MLP fc2 + sigmoid: wave per row, 4 rows/block ----------------
__global__ __launch_bounds__(256) void k_mlp2(const float* __restrict__ z,
                                              const float* __restrict__ w,
                                              const float* __restrict__ b,
                                              float* __restrict__ out) {
    int r = blockIdx.x * 4 + (threadIdx.x >> 6);
    int lane = threadIdx.x & 63;
    float acc = 0.f;
#pragma unroll
    for (int i = 0; i < 7; ++i) {
        int c = lane + i * 64;
        acc += z[(size_t)r * 448 + c] * w[c];
    }
#pragma unroll
    for (int off = 32; off > 0; off >>= 1) acc += __shfl_down(acc, off, 64);
    if (lane == 0) {
        float lg = acc + b[0];
        out[r] = 1.f / (1.f + expf(-lg));
    }
}

extern "C" void kernel_launch(void* const* d_in, const int* in_sizes, int n_in,
                              void* d_out, int out_size, void* d_ws, size_t ws_size,
                              hipStream_t stream) {
    const float* bert = (const float*)d_in[0];
    const float* x    = (const float*)d_in[1];
    const int*   ei   = (const int*)d_in[2];
    const int*   ent  = (const int*)d_in[3];
    const float* W1   = (const float*)d_in[4];
    const float* b1   = (const float*)d_in[5];
    const float* W2   = (const float*)d_in[6];
    const float* b2   = (const float*)d_in[7];
    const float* fc1w = (const float*)d_in[8];
    const float* fc1b = (const float*)d_in[9];
    const float* fc2w = (const float*)d_in[10];
    const float* fc2b = (const float*)d_in[11];
    float* out = (float*)d_out;

    const int N = in_sizes[1] / 128;   // 50000
    const int E = in_sizes[2] / 2;     // 800000
    const int B = in_sizes[0] / 768;   // 4096

    const int* srcv = ei;
    const int* dstv = ei + E;

    char* wsp = (char*)d_ws;
    size_t off = 0;
    auto alloc = [&](size_t bytes) -> void* {
        void* p = wsp + off;
        off += (bytes + 255) & ~(size_t)255;
        return p;
    };
    float* dinv   = (float*)alloc((size_t)N * 4);
    int*   incnt  = (int*)alloc((size_t)N * 4);
    int*   cur    = (int*)alloc((size_t)N * 4);
    int*   offs   = (int*)alloc((size_t)(N + 1) * 4);
    int*   bsum   = (int*)alloc(256 * 4);
    int*   boff   = (int*)alloc(256 * 4);
    int2*  csr    = (int2*)alloc((size_t)E * 8);
    bf16_t* xb    = (bf16_t*)alloc((size_t)N * 128 * 2);
    bf16_t* bertb = (bf16_t*)alloc((size_t)B * 768 * 2);
    bf16_t* w1t   = (bf16_t*)alloc(128 * 128 * 2);
    bf16_t* w2t   = (bf16_t*)alloc(128 * 128 * 2);
    bf16_t* fwt   = (bf16_t*)alloc((size_t)896 * 448 * 2);
    bf16_t* gbuf  = (bf16_t*)alloc((size_t)N * 128 * 2);
    bf16_t* hbuf  = (bf16_t*)alloc((size_t)N * 128 * 2);
    bf16_t* gnnb  = (bf16_t*)alloc((size_t)B * 128 * 2);
    float* zbuf   = (float*)alloc((size_t)B * 448 * 4);
    (void)ws_size; (void)n_in; (void)out_size;

    hipMemsetAsync(incnt, 0, (size_t)N * 4, stream);
    hipMemsetAsync(cur, 0, (size_t)N * 4, stream);

    int nb = (N + 255) / 256;
    k_count<<<(E + 255) / 256, 256, 0, stream>>>(dstv, incnt, E);
    k_dinv <<<nb, 256, 0, stream>>>(incnt, dinv, N);
    k_scan1<<<nb, 256, 0, stream>>>(incnt, offs, bsum, N);
    k_scan2<<<1, 256, 0, stream>>>(bsum, boff, nb);
    k_scan3<<<nb, 256, 0, stream>>>(offs, boff, N, E);
    k_fill <<<(E + 255) / 256, 256, 0, stream>>>(srcv, dstv, offs, cur, dinv, csr, E);

    int nx8 = N * 128 / 8, nb8 = B * 768 / 8;
    k_cvt<<<(nx8 + 255) / 256, 256, 0, stream>>>(x, (unsigned int*)xb, nx8);
    k_cvt<<<(nb8 + 255) / 256, 256, 0, stream>>>(bert, (unsigned int*)bertb, nb8);
    k_prep_wt<<<(128 * 128 + 255) / 256, 256, 0, stream>>>(W1, (unsigned short*)w1t, 128, 128);
    k_prep_wt<<<(128 * 128 + 255) / 256, 256, 0, stream>>>(W2, (unsigned short*)w2t, 128, 128);
    k_prep_wt<<<(896 * 448 + 255) / 256, 256, 0, stream>>>(fc1w, (unsigned short*)fwt, 896, 448);

    int gb = (N + 63) / 64;
    k_gemm_nn128<<<gb, 256, 0, stream>>>(xb, w1t, gbuf, N);
    k_agg_b<<<(N + 3) / 4, 256, 0, stream>>>((const unsigned int*)gbuf, csr, offs, dinv, b1,
                                             (unsigned int*)hbuf, N);
    k_gemm_nn128<<<gb, 256, 0, stream>>>(hbuf, w2t, gbuf, N);
    k_agg_b<<<(N + 3) / 4, 256, 0, stream>>>((const unsigned int*)gbuf, csr, offs, dinv, b2,
                                             (unsigned int*)hbuf, N);
    k_pool_b<<<B / 4, 256, 0, stream>>>((const unsigned int*)hbuf, ent, (unsigned int*)gnnb);
    k_mlp1_mfma<<<dim3(B / 64, 7), 256, 0, stream>>>(bertb, gnnb, fwt, fc1b, zbuf);
    k_mlp2<<<B / 4, 256, 0, stream>>>(zbuf, fc2w, fc2b, out);
}